// Round 5
// baseline (805.719 us; speedup 1.0000x reference)
//
#include <hip/hip_runtime.h>

// ---------------------------------------------------------------------------
// UniversalBlockEncoder: algebraically folded attention pooling.
//
//   u_i = silu(W1 x_i + b1)                 (the only per-point nonlinearity)
//   s_h(i) = g_h . u_i + d_h    with g_h = W2^T (scale Wk_h^T q_h)
//   p = exp(s)  (scores O(3), f32-safe without max-subtraction)
//   T_h = sum_i p_h(i) u_i ,  l_h = sum_i p_h(i)
//   out = Wo ( Wv ( W2 (T/l) + b2 ) + bv ) + bo
//
// R12: occupancy restructure. R11 counters: main 41us, VALUBusy 39%,
//      Occupancy 23% -> latency-bound; cap = 9.8KB LDS per PRIVATE wave
//      u-tile (<=14 waves/CU). Now 4 waves COOPERATE on one 64-pt group:
//      wave ws computes j-slice [16ws,16ws+16) into a SHARED u[64][72],
//      publishes per-h score partials to LDS; after barrier, wave ws
//      finalizes h=ws (4 reads + exp2) into pw; barrier; each wave runs
//      2 MFMAs on its own 16-j tile (1 f32x4 acc). LDS 14.1KB/256thr
//      -> 8 blocks/CU = 32 waves/CU (full), vs ~7 waves before.
//      Per-j math (packed f32) identical to R10. Constants via s_load (R10
//      path; R11 proved the cpk-LDS detour neutral).
// ---------------------------------------------------------------------------

#define LOG2E 1.44269504088896340736f
#define NLN2  (-0.69314718055994530942f)

#if __has_builtin(__builtin_amdgcn_exp2f)
#define EXP2(x) __builtin_amdgcn_exp2f(x)
#else
#define EXP2(x) exp2f(x)
#endif
#if __has_builtin(__builtin_amdgcn_rcpf)
#define RCP(x) __builtin_amdgcn_rcpf(x)
#else
#define RCP(x) (1.0f / (x))
#endif

// Intra-wave LDS ordering (own region; wave lockstep => lgkmcnt(0) is a
// sufficient producer-consumer barrier). Cross-wave ordering uses
// __syncthreads (which drains vmcnt/lgkmcnt before s_barrier).
#define LDS_WAIT() asm volatile("s_waitcnt lgkmcnt(0)" ::: "memory")

typedef __attribute__((ext_vector_type(8))) __bf16 bf16x8;
typedef __attribute__((ext_vector_type(4))) float  f32x4;
typedef __attribute__((ext_vector_type(2))) float  f32x2;

__device__ __forceinline__ f32x2 fma2(f32x2 a, f32x2 b, f32x2 c) {
#if __has_builtin(__builtin_elementwise_fma)
    return __builtin_elementwise_fma(a, b, c);
#else
    return (f32x2){fmaf(a.x, b.x, c.x), fmaf(a.y, b.y, c.y)};
#endif
}

// workspace float offsets
#define WS_PK   0      // 32 pairs x 16 floats (pair-SoA constants)
#define WS_D    512    // 4           : log2e * d_h
#define WS_ACC  768    // NSLOT x SLOTSTRIDE: [0..3]=l_h, [4+h*64+j]=T'_h[j]
#define NSLOT      64
#define SLOTSTRIDE 272

#define NPTS       (1024 * 1024)
#define K1_BLOCKS  2048
#define K1_THREADS 256
#define GROUPS_PER_BLOCK ((NPTS / 64) / K1_BLOCKS)    // 8

// shared LDS (shorts): u[64][72] + pw[4][72] + part/scr region
// u at 0 (4608 shorts), pw at 4608 (288 shorts; b-frag m>=4 overreads into
// the part region -> garbage contaminates only D cols h>=4, never read),
// part at 4896 shorts (float[16][68] = 1088 floats; reused as per-wave scr
// strips in the epilogue).
#define U_SH    0
#define PW_SH   4608
#define PART_SH 4896
#define SMEM_SHORTS (PART_SH + 1088 * 2)   // 7072 shorts = 14144 B

__device__ __forceinline__ unsigned short to_bf16(float x) {
    return (unsigned short)((__float_as_uint(x) + 0x8000u) >> 16);
}

// ---------------------------------------------------------------------------
// Setup: 64 blocks x 64 threads. Every block redundantly computes q and a
// (coalesced); block j computes g[j][h] lane-per-d + shuffle reduce. All
// blocks cooperatively zero the accumulator slots.
__global__ void setup_kernel(const float* __restrict__ W1, const float* __restrict__ b1,
                             const float* __restrict__ W2, const float* __restrict__ b2,
                             const float* __restrict__ query,
                             const float* __restrict__ ipw, const float* __restrict__ ipb,
                             float* __restrict__ ws)
{
    __shared__ float qv[64], qs[64], as4[4][64];
    const int t = threadIdx.x;
    const int b = blockIdx.x;     // = output j

    for (int i = b * 64 + t; i < NSLOT * SLOTSTRIDE; i += 64 * 64)
        ws[WS_ACC + i] = 0.0f;

    qv[t] = query[t];
    __syncthreads();

    {
        float a = ipb[t];
        #pragma unroll
        for (int k = 0; k < 64; ++k) a = fmaf(ipw[t * 64 + k], qv[k], a);
        qs[t] = a;
    }
    __syncthreads();

    #pragma unroll
    for (int h = 0; h < 4; ++h) {
        float a = 0.0f;
        #pragma unroll
        for (int m = 0; m < 16; ++m)
            a = fmaf(ipw[(64 + h * 16 + m) * 64 + t], qs[h * 16 + m], a);
        as4[h][t] = 0.25f * a;
    }
    __syncthreads();

    const float w2 = W2[t * 64 + b];
    float g[4];
    #pragma unroll
    for (int h = 0; h < 4; ++h) {
        float v = as4[h][t] * w2;
        for (int m = 1; m < 64; m <<= 1) v += __shfl_xor(v, m);
        g[h] = v;
    }
    if (t == 0) {
        const int base = 16 * (b >> 1);
        const int sub  = b & 1;
        ws[WS_PK + base + 0  + sub] = -LOG2E * W1[2 * b];      // cx
        ws[WS_PK + base + 2  + sub] = -LOG2E * W1[2 * b + 1];  // cy
        ws[WS_PK + base + 4  + sub] = -LOG2E * b1[b];          // cz
        ws[WS_PK + base + 6  + sub] = 0.0f;                    // pad
        ws[WS_PK + base + 8  + sub] = -g[0];                   // -g: LOG2E*NLN2 fold
        ws[WS_PK + base + 10 + sub] = -g[1];
        ws[WS_PK + base + 12 + sub] = -g[2];
        ws[WS_PK + base + 14 + sub] = -g[3];
    }
    if (b == 0 && t < 4) {
        float d = 0.0f;
        #pragma unroll
        for (int c = 0; c < 64; ++c) d += as4[t][c] * b2[c];
        float qb = 0.0f;
        #pragma unroll
        for (int m = 0; m < 16; ++m) qb += qs[t * 16 + m] * ipb[64 + t * 16 + m];
        ws[WS_D + t] = LOG2E * (d + 0.25f * qb);
    }
}

// ---------------------------------------------------------------------------
// Main: 4 waves cooperate on one 64-point group per iteration.
// Phase 1 (lane = point): wave ws computes its 16-j slice (8 packed pairs),
// writes u rows [16ws,16ws+16) of the shared tile + 4 per-h score partials.
// sync. Finalize: wave ws sums the 4 partials for h=ws, adds d_h, exp2 ->
// pw row ws, accumulates l_{ws}. sync. Phase 2: each wave 2x
// mfma_f32_16x16x32_bf16 on its own 16-j tile (A=u rows 16ws+m, B=p).
// Epilogue: per-wave transpose via scr strip (in part region) -> coalesced
// atomics; l via per-wave shuffle-reduce.
__global__ __launch_bounds__(K1_THREADS, 8) void main_kernel(
        const float* __restrict__ rr, const float* __restrict__ ri,
        const float4* __restrict__ pk4,
        const float* __restrict__ dvec, float* __restrict__ accb)
{
    __shared__ __align__(16) unsigned short smem[SMEM_SHORTS];

    const int t    = threadIdx.x;
    const int lane = t & 63;
    const int ws   = t >> 6;
    const int m    = lane & 15;
    const int q    = lane >> 4;

    unsigned short* uw = smem + U_SH;     // u: [j][pt], stride 72
    unsigned short* pw = smem + PW_SH;    // p: [h][pt], stride 72
    float* part = (float*)(smem + PART_SH);  // [w'*4+h][pt], stride 68

    const float dh = dvec[ws];            // log2e * d_{ws} (wave-uniform)
    const int jbase = ws * 8;             // this wave's first constant pair

    float lsum = 0.0f;
    f32x4 acc = (f32x4){0.f, 0.f, 0.f, 0.f};

    // hoist ALL global loads to kernel entry (all 4 waves load the same
    // points -> L1 absorbs the redundancy)
    float rv[GROUPS_PER_BLOCK], iv[GROUPS_PER_BLOCK];
    #pragma unroll
    for (int it = 0; it < GROUPS_PER_BLOCK; ++it) {
        const int idx = (blockIdx.x + it * K1_BLOCKS) * 64 + lane;
        rv[it] = rr[idx];
        iv[it] = ri[idx];
    }

    for (int it = 0; it < GROUPS_PER_BLOCK; ++it) {
        const f32x2 r2 = {rv[it], rv[it]};
        const f32x2 i2 = {iv[it], iv[it]};

        // packed score partials over this wave's 16-j slice
        f32x2 s0v = {0.f, 0.f}, s1v = {0.f, 0.f}, s2v = {0.f, 0.f}, s3v = {0.f, 0.f};

        #pragma unroll
        for (int jj = 0; jj < 8; ++jj) {
            const int jp = jbase + jj;                  // wave-uniform
            const float4 A  = pk4[4 * jp + 0];   // {cx0,cx1,cy0,cy1} -> s_load
            const float4 B  = pk4[4 * jp + 1];   // {cz0,cz1, 0, 0 }
            const float4 C  = pk4[4 * jp + 2];   // {g00,g01,g10,g11}
            const float4 Dv = pk4[4 * jp + 3];   // {g20,g21,g30,g31}

            const f32x2 cx = {A.x, A.y};
            const f32x2 cy = {A.z, A.w};
            const f32x2 cz = {B.x, B.y};

            const f32x2 zn = fma2(cx, r2, fma2(cy, i2, cz));     // -log2e * z
            const f32x2 e  = {EXP2(zn.x), EXP2(zn.y)};           // exp(-z)
            const f32x2 op = e + (f32x2){1.f, 1.f};
            const f32x2 rc = {RCP(op.x), RCP(op.y)};             // sigmoid(z)
            const f32x2 ub = zn * rc;            // = u / NLN2  (fold)

            s0v = fma2((f32x2){C.x,  C.y},  ub, s0v);
            s1v = fma2((f32x2){C.z,  C.w},  ub, s1v);
            s2v = fma2((f32x2){Dv.x, Dv.y}, ub, s2v);
            s3v = fma2((f32x2){Dv.z, Dv.w}, ub, s3v);

            uw[(2 * jp)     * 72 + lane] = to_bf16(ub.x);   // row 16ws+2jj
            uw[(2 * jp + 1) * 72 + lane] = to_bf16(ub.y);   // row 16ws+2jj+1
        }
        // publish per-h partials for this wave's slice
        part[(ws * 4 + 0) * 68 + lane] = s0v.x + s0v.y;
        part[(ws * 4 + 1) * 68 + lane] = s1v.x + s1v.y;
        part[(ws * 4 + 2) * 68 + lane] = s2v.x + s2v.y;
        part[(ws * 4 + 3) * 68 + lane] = s3v.x + s3v.y;
        __syncthreads();   // u + partials visible block-wide (drains lgkm)

        // finalize h = ws: sum the 4 wave-partials, exp2, publish p row
        {
            const float s = dh + part[(0 * 4 + ws) * 68 + lane]
                               + part[(1 * 4 + ws) * 68 + lane]
                               + part[(2 * 4 + ws) * 68 + lane]
                               + part[(3 * 4 + ws) * 68 + lane];
            const float p = EXP2(s);
            lsum += p;
            pw[ws * 72 + lane] = to_bf16(p);
        }
        __syncthreads();   // pw visible block-wide

        // phase 2: this wave's 16-j tile x all 64 points
        const bf16x8 b0 = *(const bf16x8*)(pw + m * 72 + q * 8);
        const bf16x8 b1 = *(const bf16x8*)(pw + m * 72 + q * 8 + 32);
        const bf16x8 a0 = *(const bf16x8*)(uw + (16 * ws + m) * 72 + q * 8);
        const bf16x8 a1 = *(const bf16x8*)(uw + (16 * ws + m) * 72 + q * 8 + 32);
        acc = __builtin_amdgcn_mfma_f32_16x16x32_bf16(a0, b0, acc, 0, 0, 0);
        acc = __builtin_amdgcn_mfma_f32_16x16x32_bf16(a1, b1, acc, 0, 0, 0);
        LDS_WAIT();   // own reads done before next group's own-row writes (WAR)
    }

    // l_{ws}: lane-local partials -> wave reduce
    for (int mm = 1; mm < 64; mm <<= 1) lsum += __shfl_xor(lsum, mm);

    // ---- epilogue: per-wave transpose D via scr strip -> coalesced atomics
    // D: row = q*4 + reg = j_local, col = m = h (cols 4..15 garbage).
    // scr strip: part + ws*80 floats, [4 h][16 j] stride 17, intra-wave only.
    float* scr = ((float*)(smem + PART_SH)) + ws * 80;
    if (m < 4) {
        #pragma unroll
        for (int reg = 0; reg < 4; ++reg)
            scr[m * 17 + q * 4 + reg] = acc[reg];
    }
    LDS_WAIT();
    const float Th = scr[(lane >> 4) * 17 + (lane & 15)];

    float* accS = accb + (blockIdx.x & (NSLOT - 1)) * SLOTSTRIDE;
    if (lane == 0) atomicAdd(accS + ws, lsum);
    atomicAdd(accS + 4 + (lane >> 4) * 64 + 16 * ws + (lane & 15), Th);
}

// ---------------------------------------------------------------------------
__global__ void finish_kernel(const float* __restrict__ W2, const float* __restrict__ b2,
                              const float* __restrict__ ipw, const float* __restrict__ ipb,
                              const float* __restrict__ opw, const float* __restrict__ opb,
                              const float* __restrict__ ws, float* __restrict__ out)
{
    __shared__ float red[260];   // [0..3]=l, [4+h*64+k]=T'
    __shared__ float sb[256];    // S-bar per (h, j)
    __shared__ float pl[64];     // pooled
    const int t = threadIdx.x;

    {
        float a = 0.0f;
        for (int s = 0; s < NSLOT; ++s) a += ws[WS_ACC + s * SLOTSTRIDE + t];
        red[t] = a;
        if (t < 4) {
            float a2 = 0.0f;
            for (int s = 0; s < NSLOT; ++s) a2 += ws[WS_ACC + s * SLOTSTRIDE + 256 + t];
            red[256 + t] = a2;
        }
    }
    __syncthreads();

    // S-bar_h[j] = W2[j][:] . (NLN2 * T'_h / l_h) + b2[j]
    {
        const int h = t >> 6, j = t & 63;
        const float inv = NLN2 / red[h];
        float a = 0.0f;
        #pragma unroll
        for (int k = 0; k < 64; ++k) a += W2[j * 64 + k] * red[4 + h * 64 + k];
        sb[t] = fmaf(inv, a, b2[j]);
    }
    __syncthreads();

    if (t < 64) {
        const int h = t >> 4;
        float a = ipb[128 + t];
        #pragma unroll
        for (int d = 0; d < 64; ++d) a += ipw[(128 + t) * 64 + d] * sb[h * 64 + d];
        pl[t] = a;
    }
    __syncthreads();

    if (t < 64) {
        float a = opb[t];
        #pragma unroll
        for (int p = 0; p < 64; ++p) a += opw[t * 64 + p] * pl[p];
        out[t] = a;
    }
}

// ---------------------------------------------------------------------------
extern "C" void kernel_launch(void* const* d_in, const int* in_sizes, int n_in,
                              void* d_out, int out_size, void* d_ws, size_t ws_size,
                              hipStream_t stream)
{
    const float* rr  = (const float*)d_in[0];   // rho_real
    const float* ri  = (const float*)d_in[1];   // rho_imag
    // d_in[2..5]: l_A, l_B, Z_A, Z_B — unused by the reference
    const float* W1  = (const float*)d_in[6];
    const float* b1  = (const float*)d_in[7];
    const float* W2  = (const float*)d_in[8];
    const float* b2  = (const float*)d_in[9];
    const float* qy  = (const float*)d_in[10];
    const float* ipw = (const float*)d_in[11];
    const float* ipb = (const float*)d_in[12];
    const float* opw = (const float*)d_in[13];
    const float* opb = (const float*)d_in[14];
    float* ws  = (float*)d_ws;
    float* out = (float*)d_out;

    setup_kernel<<<64, 64, 0, stream>>>(W1, b1, W2, b2, qy, ipw, ipb, ws);
    main_kernel<<<K1_BLOCKS, K1_THREADS, 0, stream>>>(
        rr, ri,
        (const float4*)(ws + WS_PK),
        ws + WS_D, ws + WS_ACC);
    finish_kernel<<<1, 256, 0, stream>>>(W2, b2, ipw, ipb, opw, opb, ws, out);
}

// Round 6
// 130.320 us; speedup vs baseline: 6.1826x; 6.1826x over previous
//
#include <hip/hip_runtime.h>

// ---------------------------------------------------------------------------
// UniversalBlockEncoder: algebraically folded attention pooling.
//
//   u_i = silu(W1 x_i + b1)                 (the only per-point nonlinearity)
//   s_h(i) = g_h . u_i + d_h    with g_h = W2^T (scale Wk_h^T q_h)
//   p = exp(s)  (scores O(3), f32-safe without max-subtraction)
//   T_h = sum_i p_h(i) u_i ,  l_h = sum_i p_h(i)
//   out = Wo ( Wv ( W2 (T/l) + b2 ) + bv ) + bo
//
// R13: R12's cooperative 4-wave structure, de-spilled. R12's
//      __launch_bounds__(256,8) clamped the allocator to 32 VGPRs ->
//      hoisted rv[8]/iv[8] + loop state spilled to scratch: FETCH 1.75GB,
//      WRITE 454MB, main 721us at VALUBusy 3%. Fix: (a) plain
//      __launch_bounds__(256) (allocator free, ~50-64 VGPR expected);
//      (b) per-group global loads instead of the 8-deep hoist (TLP at
//      16-32 waves/CU hides the L2/L3 latency). Structure, LDS layout
//      (14.3KB/block), barriers, MFMA, epilogue: unchanged from R12.
// ---------------------------------------------------------------------------

#define LOG2E 1.44269504088896340736f
#define NLN2  (-0.69314718055994530942f)

#if __has_builtin(__builtin_amdgcn_exp2f)
#define EXP2(x) __builtin_amdgcn_exp2f(x)
#else
#define EXP2(x) exp2f(x)
#endif
#if __has_builtin(__builtin_amdgcn_rcpf)
#define RCP(x) __builtin_amdgcn_rcpf(x)
#else
#define RCP(x) (1.0f / (x))
#endif

// Intra-wave LDS ordering (own region; wave lockstep => lgkmcnt(0) is a
// sufficient producer-consumer barrier). Cross-wave ordering uses
// __syncthreads (which drains vmcnt/lgkmcnt before s_barrier).
#define LDS_WAIT() asm volatile("s_waitcnt lgkmcnt(0)" ::: "memory")

typedef __attribute__((ext_vector_type(8))) __bf16 bf16x8;
typedef __attribute__((ext_vector_type(4))) float  f32x4;
typedef __attribute__((ext_vector_type(2))) float  f32x2;

__device__ __forceinline__ f32x2 fma2(f32x2 a, f32x2 b, f32x2 c) {
#if __has_builtin(__builtin_elementwise_fma)
    return __builtin_elementwise_fma(a, b, c);
#else
    return (f32x2){fmaf(a.x, b.x, c.x), fmaf(a.y, b.y, c.y)};
#endif
}

// workspace float offsets
#define WS_PK   0      // 32 pairs x 16 floats (pair-SoA constants)
#define WS_D    512    // 4           : log2e * d_h
#define WS_ACC  768    // NSLOT x SLOTSTRIDE: [0..3]=l_h, [4+h*64+j]=T'_h[j]
#define NSLOT      64
#define SLOTSTRIDE 272

#define NPTS       (1024 * 1024)
#define K1_BLOCKS  2048
#define K1_THREADS 256
#define GROUPS_PER_BLOCK ((NPTS / 64) / K1_BLOCKS)    // 8

// shared LDS (shorts): u[64][72] + pw[4][72] + part/scr region
// u at 0 (4608 shorts), pw at 4608 (288 shorts; b-frag m>=4 overreads into
// the part region -> garbage contaminates only D cols h>=4, never read),
// part at 4896 shorts (float[16][68] = 1088 floats; reused as per-wave scr
// strips in the epilogue).
#define U_SH    0
#define PW_SH   4608
#define PART_SH 4896
#define SMEM_SHORTS (PART_SH + 1088 * 2)   // 7072 shorts = 14144 B

__device__ __forceinline__ unsigned short to_bf16(float x) {
    return (unsigned short)((__float_as_uint(x) + 0x8000u) >> 16);
}

// ---------------------------------------------------------------------------
// Setup: 64 blocks x 64 threads. Every block redundantly computes q and a
// (coalesced); block j computes g[j][h] lane-per-d + shuffle reduce. All
// blocks cooperatively zero the accumulator slots.
__global__ void setup_kernel(const float* __restrict__ W1, const float* __restrict__ b1,
                             const float* __restrict__ W2, const float* __restrict__ b2,
                             const float* __restrict__ query,
                             const float* __restrict__ ipw, const float* __restrict__ ipb,
                             float* __restrict__ ws)
{
    __shared__ float qv[64], qs[64], as4[4][64];
    const int t = threadIdx.x;
    const int b = blockIdx.x;     // = output j

    for (int i = b * 64 + t; i < NSLOT * SLOTSTRIDE; i += 64 * 64)
        ws[WS_ACC + i] = 0.0f;

    qv[t] = query[t];
    __syncthreads();

    {
        float a = ipb[t];
        #pragma unroll
        for (int k = 0; k < 64; ++k) a = fmaf(ipw[t * 64 + k], qv[k], a);
        qs[t] = a;
    }
    __syncthreads();

    #pragma unroll
    for (int h = 0; h < 4; ++h) {
        float a = 0.0f;
        #pragma unroll
        for (int m = 0; m < 16; ++m)
            a = fmaf(ipw[(64 + h * 16 + m) * 64 + t], qs[h * 16 + m], a);
        as4[h][t] = 0.25f * a;
    }
    __syncthreads();

    const float w2 = W2[t * 64 + b];
    float g[4];
    #pragma unroll
    for (int h = 0; h < 4; ++h) {
        float v = as4[h][t] * w2;
        for (int m = 1; m < 64; m <<= 1) v += __shfl_xor(v, m);
        g[h] = v;
    }
    if (t == 0) {
        const int base = 16 * (b >> 1);
        const int sub  = b & 1;
        ws[WS_PK + base + 0  + sub] = -LOG2E * W1[2 * b];      // cx
        ws[WS_PK + base + 2  + sub] = -LOG2E * W1[2 * b + 1];  // cy
        ws[WS_PK + base + 4  + sub] = -LOG2E * b1[b];          // cz
        ws[WS_PK + base + 6  + sub] = 0.0f;                    // pad
        ws[WS_PK + base + 8  + sub] = -g[0];                   // -g: LOG2E*NLN2 fold
        ws[WS_PK + base + 10 + sub] = -g[1];
        ws[WS_PK + base + 12 + sub] = -g[2];
        ws[WS_PK + base + 14 + sub] = -g[3];
    }
    if (b == 0 && t < 4) {
        float d = 0.0f;
        #pragma unroll
        for (int c = 0; c < 64; ++c) d += as4[t][c] * b2[c];
        float qb = 0.0f;
        #pragma unroll
        for (int m = 0; m < 16; ++m) qb += qs[t * 16 + m] * ipb[64 + t * 16 + m];
        ws[WS_D + t] = LOG2E * (d + 0.25f * qb);
    }
}

// ---------------------------------------------------------------------------
// Main: 4 waves cooperate on one 64-point group per iteration.
// Phase 1 (lane = point): wave ws computes its 16-j slice (8 packed pairs),
// writes u rows [16ws,16ws+16) of the shared tile + 4 per-h score partials.
// sync. Finalize: wave ws sums the 4 partials for h=ws, adds d_h, exp2 ->
// pw row ws, accumulates l_{ws}. sync. Phase 2: each wave 2x
// mfma_f32_16x16x32_bf16 on its own 16-j tile (A=u rows 16ws+m, B=p).
// Epilogue: per-wave transpose via scr strip (in part region) -> coalesced
// atomics; l via per-wave shuffle-reduce.
__global__ __launch_bounds__(K1_THREADS) void main_kernel(
        const float* __restrict__ rr, const float* __restrict__ ri,
        const float4* __restrict__ pk4,
        const float* __restrict__ dvec, float* __restrict__ accb)
{
    __shared__ __align__(16) unsigned short smem[SMEM_SHORTS];

    const int t    = threadIdx.x;
    const int lane = t & 63;
    const int ws   = t >> 6;
    const int m    = lane & 15;
    const int q    = lane >> 4;

    unsigned short* uw = smem + U_SH;     // u: [j][pt], stride 72
    unsigned short* pw = smem + PW_SH;    // p: [h][pt], stride 72
    float* part = (float*)(smem + PART_SH);  // [w'*4+h][pt], stride 68

    const float dh = dvec[ws];            // log2e * d_{ws} (wave-uniform)
    const int jbase = ws * 8;             // this wave's first constant pair

    float lsum = 0.0f;
    f32x4 acc = (f32x4){0.f, 0.f, 0.f, 0.f};

    for (int it = 0; it < GROUPS_PER_BLOCK; ++it) {
        // per-group loads (coalesced; 4 waves share lines via L1; latency
        // hidden by TLP at 16-32 waves/CU)
        const int idx = (blockIdx.x + it * K1_BLOCKS) * 64 + lane;
        const float r  = rr[idx];
        const float im = ri[idx];
        const f32x2 r2 = {r, r};
        const f32x2 i2 = {im, im};

        // packed score partials over this wave's 16-j slice
        f32x2 s0v = {0.f, 0.f}, s1v = {0.f, 0.f}, s2v = {0.f, 0.f}, s3v = {0.f, 0.f};

        #pragma unroll
        for (int jj = 0; jj < 8; ++jj) {
            const int jp = jbase + jj;                  // wave-uniform
            const float4 A  = pk4[4 * jp + 0];   // {cx0,cx1,cy0,cy1} -> s_load
            const float4 B  = pk4[4 * jp + 1];   // {cz0,cz1, 0, 0 }
            const float4 C  = pk4[4 * jp + 2];   // {g00,g01,g10,g11}
            const float4 Dv = pk4[4 * jp + 3];   // {g20,g21,g30,g31}

            const f32x2 cx = {A.x, A.y};
            const f32x2 cy = {A.z, A.w};
            const f32x2 cz = {B.x, B.y};

            const f32x2 zn = fma2(cx, r2, fma2(cy, i2, cz));     // -log2e * z
            const f32x2 e  = {EXP2(zn.x), EXP2(zn.y)};           // exp(-z)
            const f32x2 op = e + (f32x2){1.f, 1.f};
            const f32x2 rc = {RCP(op.x), RCP(op.y)};             // sigmoid(z)
            const f32x2 ub = zn * rc;            // = u / NLN2  (fold)

            s0v = fma2((f32x2){C.x,  C.y},  ub, s0v);
            s1v = fma2((f32x2){C.z,  C.w},  ub, s1v);
            s2v = fma2((f32x2){Dv.x, Dv.y}, ub, s2v);
            s3v = fma2((f32x2){Dv.z, Dv.w}, ub, s3v);

            uw[(2 * jp)     * 72 + lane] = to_bf16(ub.x);   // row 16ws+2jj
            uw[(2 * jp + 1) * 72 + lane] = to_bf16(ub.y);   // row 16ws+2jj+1
        }
        // publish per-h partials for this wave's slice
        part[(ws * 4 + 0) * 68 + lane] = s0v.x + s0v.y;
        part[(ws * 4 + 1) * 68 + lane] = s1v.x + s1v.y;
        part[(ws * 4 + 2) * 68 + lane] = s2v.x + s2v.y;
        part[(ws * 4 + 3) * 68 + lane] = s3v.x + s3v.y;
        __syncthreads();   // u + partials visible block-wide (drains lgkm)

        // finalize h = ws: sum the 4 wave-partials, exp2, publish p row
        {
            const float s = dh + part[(0 * 4 + ws) * 68 + lane]
                               + part[(1 * 4 + ws) * 68 + lane]
                               + part[(2 * 4 + ws) * 68 + lane]
                               + part[(3 * 4 + ws) * 68 + lane];
            const float p = EXP2(s);
            lsum += p;
            pw[ws * 72 + lane] = to_bf16(p);
        }
        __syncthreads();   // pw visible block-wide

        // phase 2: this wave's 16-j tile x all 64 points
        const bf16x8 b0 = *(const bf16x8*)(pw + m * 72 + q * 8);
        const bf16x8 b1 = *(const bf16x8*)(pw + m * 72 + q * 8 + 32);
        const bf16x8 a0 = *(const bf16x8*)(uw + (16 * ws + m) * 72 + q * 8);
        const bf16x8 a1 = *(const bf16x8*)(uw + (16 * ws + m) * 72 + q * 8 + 32);
        acc = __builtin_amdgcn_mfma_f32_16x16x32_bf16(a0, b0, acc, 0, 0, 0);
        acc = __builtin_amdgcn_mfma_f32_16x16x32_bf16(a1, b1, acc, 0, 0, 0);
        LDS_WAIT();   // own reads done before next group's own-row writes (WAR)
    }

    // l_{ws}: lane-local partials -> wave reduce
    for (int mm = 1; mm < 64; mm <<= 1) lsum += __shfl_xor(lsum, mm);

    // ---- epilogue: per-wave transpose D via scr strip -> coalesced atomics
    // D: row = q*4 + reg = j_local, col = m = h (cols 4..15 garbage).
    // scr strip: part + ws*80 floats, [4 h][16 j] stride 17, intra-wave only.
    float* scr = ((float*)(smem + PART_SH)) + ws * 80;
    if (m < 4) {
        #pragma unroll
        for (int reg = 0; reg < 4; ++reg)
            scr[m * 17 + q * 4 + reg] = acc[reg];
    }
    LDS_WAIT();
    const float Th = scr[(lane >> 4) * 17 + (lane & 15)];

    float* accS = accb + (blockIdx.x & (NSLOT - 1)) * SLOTSTRIDE;
    if (lane == 0) atomicAdd(accS + ws, lsum);
    atomicAdd(accS + 4 + (lane >> 4) * 64 + 16 * ws + (lane & 15), Th);
}

// ---------------------------------------------------------------------------
__global__ void finish_kernel(const float* __restrict__ W2, const float* __restrict__ b2,
                              const float* __restrict__ ipw, const float* __restrict__ ipb,
                              const float* __restrict__ opw, const float* __restrict__ opb,
                              const float* __restrict__ ws, float* __restrict__ out)
{
    __shared__ float red[260];   // [0..3]=l, [4+h*64+k]=T'
    __shared__ float sb[256];    // S-bar per (h, j)
    __shared__ float pl[64];     // pooled
    const int t = threadIdx.x;

    {
        float a = 0.0f;
        for (int s = 0; s < NSLOT; ++s) a += ws[WS_ACC + s * SLOTSTRIDE + t];
        red[t] = a;
        if (t < 4) {
            float a2 = 0.0f;
            for (int s = 0; s < NSLOT; ++s) a2 += ws[WS_ACC + s * SLOTSTRIDE + 256 + t];
            red[256 + t] = a2;
        }
    }
    __syncthreads();

    // S-bar_h[j] = W2[j][:] . (NLN2 * T'_h / l_h) + b2[j]
    {
        const int h = t >> 6, j = t & 63;
        const float inv = NLN2 / red[h];
        float a = 0.0f;
        #pragma unroll
        for (int k = 0; k < 64; ++k) a += W2[j * 64 + k] * red[4 + h * 64 + k];
        sb[t] = fmaf(inv, a, b2[j]);
    }
    __syncthreads();

    if (t < 64) {
        const int h = t >> 4;
        float a = ipb[128 + t];
        #pragma unroll
        for (int d = 0; d < 64; ++d) a += ipw[(128 + t) * 64 + d] * sb[h * 64 + d];
        pl[t] = a;
    }
    __syncthreads();

    if (t < 64) {
        float a = opb[t];
        #pragma unroll
        for (int p = 0; p < 64; ++p) a += opw[t * 64 + p] * pl[p];
        out[t] = a;
    }
}

// ---------------------------------------------------------------------------
extern "C" void kernel_launch(void* const* d_in, const int* in_sizes, int n_in,
                              void* d_out, int out_size, void* d_ws, size_t ws_size,
                              hipStream_t stream)
{
    const float* rr  = (const float*)d_in[0];   // rho_real
    const float* ri  = (const float*)d_in[1];   // rho_imag
    // d_in[2..5]: l_A, l_B, Z_A, Z_B — unused by the reference
    const float* W1  = (const float*)d_in[6];
    const float* b1  = (const float*)d_in[7];
    const float* W2  = (const float*)d_in[8];
    const float* b2  = (const float*)d_in[9];
    const float* qy  = (const float*)d_in[10];
    const float* ipw = (const float*)d_in[11];
    const float* ipb = (const float*)d_in[12];
    const float* opw = (const float*)d_in[13];
    const float* opb = (const float*)d_in[14];
    float* ws  = (float*)d_ws;
    float* out = (float*)d_out;

    setup_kernel<<<64, 64, 0, stream>>>(W1, b1, W2, b2, qy, ipw, ipb, ws);
    main_kernel<<<K1_BLOCKS, K1_THREADS, 0, stream>>>(
        rr, ri,
        (const float4*)(ws + WS_PK),
        ws + WS_D, ws + WS_ACC);
    finish_kernel<<<1, 256, 0, stream>>>(W2, b2, ipw, ipb, opw, opb, ws, out);
}

// Round 7
// 122.699 us; speedup vs baseline: 6.5666x; 1.0621x over previous
//
#include <hip/hip_runtime.h>

// ---------------------------------------------------------------------------
// UniversalBlockEncoder: algebraically folded attention pooling.
//
//   u_i = silu(W1 x_i + b1)                 (the only per-point nonlinearity)
//   s_h(i) = g_h . u_i + d_h    with g_h = W2^T (scale Wk_h^T q_h)
//   p = exp(s)  (scores O(3), f32-safe without max-subtraction)
//   T_h = sum_i p_h(i) u_i ,  l_h = sum_i p_h(i)
//   out = Wo ( Wv ( W2 (T/l) + b2 ) + bv ) + bo
//
// R14: trans-pipe probe/fix on the proven R10 base (121.7us). Evidence:
//      R10/R11/R13 (3 different structures) all pin main at 41+-1.5us,
//      VALUBusy ~40%, Mfma 2%, no conflicts, no HBM -> shared-pipe limit.
//      Only invariant: 132 trans ops/point (64 v_exp + 64 v_rcp + 4 exp2)
//      = 45 cyc/wave-trans effective if pipe-bound: matches 40us exactly.
//      Change: v_rcp -> bit-magic seed (0x7EF311C3 - i) + 2 Newton iters
//      in packed f32 (2x v_pk_fma each): trans/pt 132 -> 68 (-48%).
//      Accuracy: sigma rel err ~1e-4 << bf16 staging quantum (4e-3),
//      and averages over 1M points. Everything else byte-identical to R10.
// ---------------------------------------------------------------------------

#define LOG2E 1.44269504088896340736f
#define NLN2  (-0.69314718055994530942f)

#if __has_builtin(__builtin_amdgcn_exp2f)
#define EXP2(x) __builtin_amdgcn_exp2f(x)
#else
#define EXP2(x) exp2f(x)
#endif

// LDS-only ordering within a wave (each wave touches only its own region;
// wave lockstep => lgkmcnt(0) is a sufficient producer-consumer barrier).
#define LDS_WAIT() asm volatile("s_waitcnt lgkmcnt(0)" ::: "memory")

typedef __attribute__((ext_vector_type(8))) __bf16 bf16x8;
typedef __attribute__((ext_vector_type(4))) float  f32x4;
typedef __attribute__((ext_vector_type(2))) float  f32x2;

__device__ __forceinline__ f32x2 fma2(f32x2 a, f32x2 b, f32x2 c) {
#if __has_builtin(__builtin_elementwise_fma)
    return __builtin_elementwise_fma(a, b, c);
#else
    return (f32x2){fmaf(a.x, b.x, c.x), fmaf(a.y, b.y, c.y)};
#endif
}

// packed reciprocal of x in (1, +inf): bit-magic seed + 2 Newton steps.
// seed rel err ~0.1 -> 1e-2 -> ~1e-4. No v_rcp (trans pipe) involved.
__device__ __forceinline__ f32x2 rcp2_nr(f32x2 x) {
    const f32x2 two = {2.f, 2.f};
    f32x2 y = {__uint_as_float(0x7EF311C3u - __float_as_uint(x.x)),
               __uint_as_float(0x7EF311C3u - __float_as_uint(x.y))};
    y = y * fma2((f32x2){-x.x, -x.y}, y, two);   // NR1: y *= (2 - x*y)
    y = y * fma2((f32x2){-x.x, -x.y}, y, two);   // NR2
    return y;
}

// workspace float offsets
#define WS_PK   0      // 32 pairs x 16 floats (pair-SoA constants)
#define WS_D    512    // 4           : log2e * d_h
#define WS_ACC  768    // NSLOT x SLOTSTRIDE: [0..3]=l_h, [4+h*64+j]=T'_h[j]
#define NSLOT      64
#define SLOTSTRIDE 272

#define NPTS       (1024 * 1024)
#define K1_BLOCKS  2048
#define K1_THREADS 128
#define WAVES_TOTAL (K1_BLOCKS * 2)                   // 4096
#define GROUPS_PER_WAVE ((NPTS / 64) / WAVES_TOTAL)   // 4

// per-wave LDS region (shorts): p[4 x 72] + u[64 x 72]
#define PW_SHORTS  288
#define UW_SHORTS  (64 * 72)
#define WAVE_SHORTS (PW_SHORTS + UW_SHORTS)  // 4896 shorts (9792 B)

__device__ __forceinline__ unsigned short to_bf16(float x) {
    return (unsigned short)((__float_as_uint(x) + 0x8000u) >> 16);
}

// ---------------------------------------------------------------------------
// Setup: 64 blocks x 64 threads. Every block redundantly computes q and a
// (coalesced); block j computes g[j][h] lane-per-d + shuffle reduce. All
// blocks cooperatively zero the accumulator slots.
__global__ void setup_kernel(const float* __restrict__ W1, const float* __restrict__ b1,
                             const float* __restrict__ W2, const float* __restrict__ b2,
                             const float* __restrict__ query,
                             const float* __restrict__ ipw, const float* __restrict__ ipb,
                             float* __restrict__ ws)
{
    __shared__ float qv[64], qs[64], as4[4][64];
    const int t = threadIdx.x;
    const int b = blockIdx.x;     // = output j

    for (int i = b * 64 + t; i < NSLOT * SLOTSTRIDE; i += 64 * 64)
        ws[WS_ACC + i] = 0.0f;

    qv[t] = query[t];
    __syncthreads();

    {
        float a = ipb[t];
        #pragma unroll
        for (int k = 0; k < 64; ++k) a = fmaf(ipw[t * 64 + k], qv[k], a);
        qs[t] = a;
    }
    __syncthreads();

    #pragma unroll
    for (int h = 0; h < 4; ++h) {
        float a = 0.0f;
        #pragma unroll
        for (int m = 0; m < 16; ++m)
            a = fmaf(ipw[(64 + h * 16 + m) * 64 + t], qs[h * 16 + m], a);
        as4[h][t] = 0.25f * a;
    }
    __syncthreads();

    const float w2 = W2[t * 64 + b];
    float g[4];
    #pragma unroll
    for (int h = 0; h < 4; ++h) {
        float v = as4[h][t] * w2;
        for (int m = 1; m < 64; m <<= 1) v += __shfl_xor(v, m);
        g[h] = v;
    }
    if (t == 0) {
        const int base = 16 * (b >> 1);
        const int sub  = b & 1;
        ws[WS_PK + base + 0  + sub] = -LOG2E * W1[2 * b];      // cx
        ws[WS_PK + base + 2  + sub] = -LOG2E * W1[2 * b + 1];  // cy
        ws[WS_PK + base + 4  + sub] = -LOG2E * b1[b];          // cz
        ws[WS_PK + base + 6  + sub] = 0.0f;                    // pad
        ws[WS_PK + base + 8  + sub] = -g[0];                   // -g: LOG2E*NLN2 fold
        ws[WS_PK + base + 10 + sub] = -g[1];
        ws[WS_PK + base + 12 + sub] = -g[2];
        ws[WS_PK + base + 14 + sub] = -g[3];
    }
    if (b == 0 && t < 4) {
        float d = 0.0f;
        #pragma unroll
        for (int c = 0; c < 64; ++c) d += as4[t][c] * b2[c];
        float qb = 0.0f;
        #pragma unroll
        for (int m = 0; m < 16; ++m) qb += qs[t * 16 + m] * ipb[64 + t * 16 + m];
        ws[WS_D + t] = LOG2E * (d + 0.25f * qb);
    }
}

// ---------------------------------------------------------------------------
// Main: 2 independent waves/block (own LDS regions; pure-lgkm waits).
// Phase 1 (lane = point): hidden units in PAIRS via packed f32 math;
// sigmoid = exp2 + Newton reciprocal (no v_rcp). Phase 2: 8x
// mfma_f32_16x16x32_bf16 per group. Epilogue: per-wave transpose D via
// LDS; block-combine across the two waves; wave 0 issues coalesced atomics.
__global__ __launch_bounds__(K1_THREADS) void main_kernel(
        const float* __restrict__ rr, const float* __restrict__ ri,
        const float4* __restrict__ pk4,
        const float* __restrict__ dvec, float* __restrict__ accb)
{
    __shared__ __align__(16) unsigned short lds[2][WAVE_SHORTS];

    const int t    = threadIdx.x;
    const int lane = t & 63;
    const int w    = t >> 6;
    const int m    = lane & 15;
    const int q    = lane >> 4;

    unsigned short* pw = lds[w];               // p: [h][pt], stride 72
    unsigned short* uw = lds[w] + PW_SHORTS;   // u: [j][pt], stride 72

    const float d0 = dvec[0], d1 = dvec[1], d2 = dvec[2], d3 = dvec[3];

    const int gwave = blockIdx.x * 2 + w;
    float l0 = 0, l1 = 0, l2 = 0, l3 = 0;
    f32x4 acc[4];
    #pragma unroll
    for (int i = 0; i < 4; ++i) acc[i] = (f32x4){0.f, 0.f, 0.f, 0.f};

    // hoist ALL global loads to kernel entry
    float rv[GROUPS_PER_WAVE], iv[GROUPS_PER_WAVE];
    #pragma unroll
    for (int it = 0; it < GROUPS_PER_WAVE; ++it) {
        const int idx = (gwave + it * WAVES_TOTAL) * 64 + lane;
        rv[it] = rr[idx];
        iv[it] = ri[idx];
    }

    for (int it = 0; it < GROUPS_PER_WAVE; ++it) {
        const f32x2 r2 = {rv[it], rv[it]};
        const f32x2 i2 = {iv[it], iv[it]};

        // packed score partials; halves summed after the loop
        f32x2 s0v = {d0, 0.f}, s1v = {d1, 0.f}, s2v = {d2, 0.f}, s3v = {d3, 0.f};

        #pragma unroll 8
        for (int jp = 0; jp < 32; ++jp) {
            const float4 A  = pk4[4 * jp + 0];   // {cx0,cx1,cy0,cy1} wave-uniform
            const float4 B  = pk4[4 * jp + 1];   // {cz0,cz1, 0, 0 }
            const float4 C  = pk4[4 * jp + 2];   // {g00,g01,g10,g11}
            const float4 Dv = pk4[4 * jp + 3];   // {g20,g21,g30,g31}

            const f32x2 cx = {A.x, A.y};
            const f32x2 cy = {A.z, A.w};
            const f32x2 cz = {B.x, B.y};

            const f32x2 zn = fma2(cx, r2, fma2(cy, i2, cz));     // -log2e * z
            const f32x2 e  = {EXP2(zn.x), EXP2(zn.y)};           // exp(-z) (trans)
            const f32x2 op = e + (f32x2){1.f, 1.f};
            const f32x2 rc = rcp2_nr(op);        // sigmoid(z), no v_rcp
            const f32x2 ub = zn * rc;            // = u / NLN2  (fold)

            s0v = fma2((f32x2){C.x,  C.y},  ub, s0v);
            s1v = fma2((f32x2){C.z,  C.w},  ub, s1v);
            s2v = fma2((f32x2){Dv.x, Dv.y}, ub, s2v);
            s3v = fma2((f32x2){Dv.z, Dv.w}, ub, s3v);

            uw[(2 * jp)     * 72 + lane] = to_bf16(ub.x);
            uw[(2 * jp + 1) * 72 + lane] = to_bf16(ub.y);
        }
        const float p0 = EXP2(s0v.x + s0v.y), p1 = EXP2(s1v.x + s1v.y);
        const float p2 = EXP2(s2v.x + s2v.y), p3 = EXP2(s3v.x + s3v.y);
        l0 += p0; l1 += p1; l2 += p2; l3 += p3;
        pw[0 * 72 + lane] = to_bf16(p0);
        pw[1 * 72 + lane] = to_bf16(p1);
        pw[2 * 72 + lane] = to_bf16(p2);
        pw[3 * 72 + lane] = to_bf16(p3);
        LDS_WAIT();    // writes visible to this wave's reads

        // B-frags (p), shared across j-tiles
        const bf16x8 b0 = *(const bf16x8*)(pw + m * 72 + q * 8);
        const bf16x8 b1 = *(const bf16x8*)(pw + m * 72 + q * 8 + 32);
        #pragma unroll
        for (int tt = 0; tt < 4; ++tt) {
            const bf16x8 a0 = *(const bf16x8*)(uw + (16 * tt + m) * 72 + q * 8);
            const bf16x8 a1 = *(const bf16x8*)(uw + (16 * tt + m) * 72 + q * 8 + 32);
            acc[tt] = __builtin_amdgcn_mfma_f32_16x16x32_bf16(a0, b0, acc[tt], 0, 0, 0);
            acc[tt] = __builtin_amdgcn_mfma_f32_16x16x32_bf16(a1, b1, acc[tt], 0, 0, 0);
        }
        LDS_WAIT();    // reads done before next iteration's writes (WAR)
    }

    // l: lane-local partials -> wave reduce
    for (int mm = 1; mm < 64; mm <<= 1) {
        l0 += __shfl_xor(l0, mm);
        l1 += __shfl_xor(l1, mm);
        l2 += __shfl_xor(l2, mm);
        l3 += __shfl_xor(l3, mm);
    }

    // ---- epilogue: per-wave transpose D via LDS, then block-combine ----
    // D: row = q*4 + reg = j_local(16tt..), col = m = h (cols 4..15 garbage)
    // scr[h][j], stride 66: writes <=2-way banks, reads 2-way (both free).
    float* scr = (float*)uw;   // own wave's u region (>= 268 floats available)
    if (m < 4) {
        #pragma unroll
        for (int tt = 0; tt < 4; ++tt)
            #pragma unroll
            for (int reg = 0; reg < 4; ++reg)
                scr[m * 66 + 16 * tt + 4 * q + reg] = acc[tt][reg];
    }
    // wave 1 publishes its wave-reduced l values alongside its scr
    if (w == 1 && lane == 0) {
        scr[4 * 66 + 0] = l0;
        scr[4 * 66 + 1] = l1;
        scr[4 * 66 + 2] = l2;
        scr[4 * 66 + 3] = l3;
    }
    __syncthreads();   // wave 1's scr + l visible to wave 0

    if (w == 0) {
        const float* scr1 = (const float*)(lds[1] + PW_SHORTS);
        float Th[4];
        #pragma unroll
        for (int h = 0; h < 4; ++h)
            Th[h] = scr[h * 66 + lane] + scr1[h * 66 + lane];

        float* accS = accb + (blockIdx.x & (NSLOT - 1)) * SLOTSTRIDE;
        if (lane == 0) {
            atomicAdd(accS + 0, l0 + scr1[4 * 66 + 0]);
            atomicAdd(accS + 1, l1 + scr1[4 * 66 + 1]);
            atomicAdd(accS + 2, l2 + scr1[4 * 66 + 2]);
            atomicAdd(accS + 3, l3 + scr1[4 * 66 + 3]);
        }
        atomicAdd(accS + 4 + 0 * 64 + lane, Th[0]);
        atomicAdd(accS + 4 + 1 * 64 + lane, Th[1]);
        atomicAdd(accS + 4 + 2 * 64 + lane, Th[2]);
        atomicAdd(accS + 4 + 3 * 64 + lane, Th[3]);
    }
}

// ---------------------------------------------------------------------------
__global__ void finish_kernel(const float* __restrict__ W2, const float* __restrict__ b2,
                              const float* __restrict__ ipw, const float* __restrict__ ipb,
                              const float* __restrict__ opw, const float* __restrict__ opb,
                              const float* __restrict__ ws, float* __restrict__ out)
{
    __shared__ float red[260];   // [0..3]=l, [4+h*64+k]=T'
    __shared__ float sb[256];    // S-bar per (h, j)
    __shared__ float pl[64];     // pooled
    const int t = threadIdx.x;

    {
        float a = 0.0f;
        for (int s = 0; s < NSLOT; ++s) a += ws[WS_ACC + s * SLOTSTRIDE + t];
        red[t] = a;
        if (t < 4) {
            float a2 = 0.0f;
            for (int s = 0; s < NSLOT; ++s) a2 += ws[WS_ACC + s * SLOTSTRIDE + 256 + t];
            red[256 + t] = a2;
        }
    }
    __syncthreads();

    // S-bar_h[j] = W2[j][:] . (NLN2 * T'_h / l_h) + b2[j]
    {
        const int h = t >> 6, j = t & 63;
        const float inv = NLN2 / red[h];
        float a = 0.0f;
        #pragma unroll
        for (int k = 0; k < 64; ++k) a += W2[j * 64 + k] * red[4 + h * 64 + k];
        sb[t] = fmaf(inv, a, b2[j]);
    }
    __syncthreads();

    if (t < 64) {
        const int h = t >> 4;
        float a = ipb[128 + t];
        #pragma unroll
        for (int d = 0; d < 64; ++d) a += ipw[(128 + t) * 64 + d] * sb[h * 64 + d];
        pl[t] = a;
    }
    __syncthreads();

    if (t < 64) {
        float a = opb[t];
        #pragma unroll
        for (int p = 0; p < 64; ++p) a += opw[t * 64 + p] * pl[p];
        out[t] = a;
    }
}

// ---------------------------------------------------------------------------
extern "C" void kernel_launch(void* const* d_in, const int* in_sizes, int n_in,
                              void* d_out, int out_size, void* d_ws, size_t ws_size,
                              hipStream_t stream)
{
    const float* rr  = (const float*)d_in[0];   // rho_real
    const float* ri  = (const float*)d_in[1];   // rho_imag
    // d_in[2..5]: l_A, l_B, Z_A, Z_B — unused by the reference
    const float* W1  = (const float*)d_in[6];
    const float* b1  = (const float*)d_in[7];
    const float* W2  = (const float*)d_in[8];
    const float* b2  = (const float*)d_in[9];
    const float* qy  = (const float*)d_in[10];
    const float* ipw = (const float*)d_in[11];
    const float* ipb = (const float*)d_in[12];
    const float* opw = (const float*)d_in[13];
    const float* opb = (const float*)d_in[14];
    float* ws  = (float*)d_ws;
    float* out = (float*)d_out;

    setup_kernel<<<64, 64, 0, stream>>>(W1, b1, W2, b2, qy, ipw, ipb, ws);
    main_kernel<<<K1_BLOCKS, K1_THREADS, 0, stream>>>(
        rr, ri,
        (const float4*)(ws + WS_PK),
        ws + WS_D, ws + WS_ACC);
    finish_kernel<<<1, 256, 0, stream>>>(W2, b2, ipw, ipb, opw, opb, ws, out);
}